// Round 4
// baseline (219.530 us; speedup 1.0000x reference)
//
#include <hip/hip_runtime.h>
#include <hip/hip_bf16.h>
#include <stdint.h>

#define D_ 1024
#define NSEQ 2048

typedef __attribute__((ext_vector_type(8))) short bf16x8;
typedef __attribute__((ext_vector_type(4))) float f32x4;

static __device__ __forceinline__ unsigned short f2bf(float x) {
    union { __hip_bfloat16 h; unsigned short u; } cv;
    cv.h = __float2bfloat16(x);
    return cv.u;
}

// async global->LDS, 16B per lane. LDS dest = wave-uniform base + lane*16 (HW).
static __device__ __forceinline__ void gload_lds16(const void* g, void* l) {
    __builtin_amdgcn_global_load_lds(
        (const __attribute__((address_space(1))) unsigned int*)(uintptr_t)g,
        (__attribute__((address_space(3))) unsigned int*)(uintptr_t)l, 16, 0, 0);
}

// ---------------- x fp32 -> bf16 ----------------
__global__ __launch_bounds__(256) void cvt_x(const float* __restrict__ x,
                                             __hip_bfloat16* __restrict__ xb) {
    int i = blockIdx.x * 256 + threadIdx.x;
    float4 v = reinterpret_cast<const float4*>(x)[i];
    ushort4 o;
    o.x = f2bf(v.x); o.y = f2bf(v.y); o.z = f2bf(v.z); o.w = f2bf(v.w);
    reinterpret_cast<ushort4*>(xb)[i] = o;
}

// ---------------- W [d][e] fp32 -> Wt [e][d] bf16 (3 weights stacked -> [3072][1024]) ----------------
__global__ __launch_bounds__(256) void wt_kernel(const float* __restrict__ Wq,
                                                 const float* __restrict__ Wk,
                                                 const float* __restrict__ Wv,
                                                 __hip_bfloat16* __restrict__ Wt) {
    const float* W = (blockIdx.z == 0) ? Wq : (blockIdx.z == 1) ? Wk : Wv;
    unsigned short* O = (unsigned short*)(Wt + (size_t)blockIdx.z * D_ * D_);
    __shared__ float tile[32][33];
    int r0 = blockIdx.y * 32, c0 = blockIdx.x * 32;
    int t = threadIdx.x;
    int r = t >> 3, c4 = (t & 7) * 4;
    float4 v = *reinterpret_cast<const float4*>(&W[(size_t)(r0 + r) * D_ + c0 + c4]);
    tile[r][c4 + 0] = v.x; tile[r][c4 + 1] = v.y;
    tile[r][c4 + 2] = v.z; tile[r][c4 + 3] = v.w;
    __syncthreads();
    int er = t >> 3, dc = (t & 7) * 4;
    ushort4 pk;
    pk.x = f2bf(tile[dc + 0][er]); pk.y = f2bf(tile[dc + 1][er]);
    pk.z = f2bf(tile[dc + 2][er]); pk.w = f2bf(tile[dc + 3][er]);
    *reinterpret_cast<ushort4*>(&O[(size_t)(c0 + er) * D_ + r0 + dc]) = pk;
}

// ---------------- NT GEMM, 128x128 tile, BK=32, 4 waves (2x2), 4x4 frags/wave ----------------
// MODE 0: fused QKV epilogue (o0=Q, o1=K row-major; o2=Vt transposed per batch)
// MODE 2: scores: S fp32 *1/32, causal mask, skip by>bx; per-(row, 64col-slice) partial
//         softmax stats (max, sum-exp) -> Pm/Pl (o1/o2), S in o0
template <int MODE>
__global__ __launch_bounds__(256) void gemm128(const __hip_bfloat16* __restrict__ A, int lda,
                                               const __hip_bfloat16* __restrict__ Bt, int ldb,
                                               void* __restrict__ o0, void* __restrict__ o1,
                                               void* __restrict__ o2) {
    const int bx = blockIdx.x, by = blockIdx.y, bz = blockIdx.z;
    if (MODE == 2 && by > bx) return;    // fully masked tile, never read downstream

    const __hip_bfloat16* Ab = A;
    const __hip_bfloat16* Bb = Bt;
    if (MODE == 2) { Ab += (size_t)bz * NSEQ * D_;  Bb += (size_t)bz * NSEQ * D_; }

    const int m0 = bx * 128, n0 = by * 128;

    __shared__ __hip_bfloat16 As[128 * 32];   // linear [128][32], row stride 64B
    __shared__ __hip_bfloat16 Bs[128 * 32];

    const int tid = threadIdx.x;
    const int lane = tid & 63, wid = tid >> 6;
    const int wm = wid >> 1, wn = wid & 1;
    const int lr = lane & 15, lk = lane >> 4;

    const int srow = wid * 32 + (lane >> 2);
    const int scol = (lane & 3) * 8;
    const __hip_bfloat16* aptr = Ab + (size_t)(m0 + srow) * lda + scol;
    const __hip_bfloat16* bptr = Bb + (size_t)(n0 + srow) * ldb + scol;
    char* AsW = (char*)As + wid * 2048;
    char* BsW = (char*)Bs + wid * 2048;

    f32x4 acc[4][4] = {};

    for (int k0 = 0; k0 < 1024; k0 += 32) {
        gload_lds16(aptr,                    AsW);
        gload_lds16(aptr + (size_t)16 * lda, AsW + 1024);
        gload_lds16(bptr,                    BsW);
        gload_lds16(bptr + (size_t)16 * ldb, BsW + 1024);
        aptr += 32; bptr += 32;
        __syncthreads();

        bf16x8 af[4], bfr[4];
#pragma unroll
        for (int m = 0; m < 4; ++m)
            af[m] = *reinterpret_cast<const bf16x8*>(&As[(wm * 64 + m * 16 + lr) * 32 + lk * 8]);
#pragma unroll
        for (int n = 0; n < 4; ++n)
            bfr[n] = *reinterpret_cast<const bf16x8*>(&Bs[(wn * 64 + n * 16 + lr) * 32 + lk * 8]);
#pragma unroll
        for (int m = 0; m < 4; ++m)
#pragma unroll
            for (int n = 0; n < 4; ++n)
                acc[m][n] = __builtin_amdgcn_mfma_f32_16x16x32_bf16(af[m], bfr[n], acc[m][n], 0, 0, 0);
        __syncthreads();
    }

    if (MODE == 0) {
#pragma unroll
        for (int m = 0; m < 4; ++m)
#pragma unroll
            for (int n = 0; n < 4; ++n) {
                const int rbase = m0 + wm * 64 + m * 16 + lk * 4;
                const int cbase = n0 + wn * 64 + n * 16 + lr;
                const int seg = cbase >> 10, e = cbase & 1023;
                if (seg < 2) {
                    unsigned short* C = (unsigned short*)(seg == 0 ? o0 : o1);
#pragma unroll
                    for (int j = 0; j < 4; ++j)
                        C[(size_t)(rbase + j) * D_ + e] = f2bf(acc[m][n][j]);
                } else {
                    unsigned short* Vt = (unsigned short*)o2;
                    const int b = rbase >> 11, nq = rbase & 2047;
                    ushort4 pk;
                    pk.x = f2bf(acc[m][n][0]); pk.y = f2bf(acc[m][n][1]);
                    pk.z = f2bf(acc[m][n][2]); pk.w = f2bf(acc[m][n][3]);
                    *reinterpret_cast<ushort4*>(&Vt[(((size_t)b << 10) + e) * NSEQ + nq]) = pk;
                }
            }
    } else {
        // scale + mask into acc, store S
        float* S = (float*)o0 + (size_t)bz * NSEQ * NSEQ;
#pragma unroll
        for (int m = 0; m < 4; ++m)
#pragma unroll
            for (int n = 0; n < 4; ++n) {
                const int rbase = m0 + wm * 64 + m * 16 + lk * 4;
                const int cbase = n0 + wn * 64 + n * 16 + lr;
#pragma unroll
                for (int j = 0; j < 4; ++j) {
                    float s = acc[m][n][j] * 0.03125f;    // 1/sqrt(1024)
                    if (cbase > rbase + j) s = -1e30f;
                    acc[m][n][j] = s;
                    S[(size_t)(rbase + j) * NSEQ + cbase] = s;
                }
            }
        // per-(row, 64-col slice) partial softmax stats; slice col index = by*2 + wn
        float* Pm = (float*)o1;
        float* Pl = (float*)o2;
        const int pcol = by * 2 + wn;
#pragma unroll
        for (int m = 0; m < 4; ++m)
#pragma unroll
            for (int j = 0; j < 4; ++j) {
                float mx = fmaxf(fmaxf(acc[m][0][j], acc[m][1][j]),
                                 fmaxf(acc[m][2][j], acc[m][3][j]));
#pragma unroll
                for (int w = 1; w < 16; w <<= 1) mx = fmaxf(mx, __shfl_xor(mx, w, 64));
                float sm = __expf(acc[m][0][j] - mx) + __expf(acc[m][1][j] - mx) +
                           __expf(acc[m][2][j] - mx) + __expf(acc[m][3][j] - mx);
#pragma unroll
                for (int w = 1; w < 16; w <<= 1) sm += __shfl_xor(sm, w, 64);
                if (lr == 0) {
                    const int row = bz * NSEQ + m0 + wm * 64 + m * 16 + lk * 4 + j;
                    Pm[row * 32 + pcol] = mx;
                    Pl[row * 32 + pcol] = sm;
                }
            }
    }
}

// ---------------- merge partial stats -> per-row (max, 1/sum) ----------------
__global__ __launch_bounds__(256) void merge_stats(const float* __restrict__ Pm,
                                                   const float* __restrict__ Pl,
                                                   float2* __restrict__ rl) {
    int row = blockIdx.x * 256 + threadIdx.x;   // 0..8191
    int q = row & 2047;
    int nc = 2 * ((q >> 7) + 1);
    float m = -3e38f, l = 0.f;
    for (int c = 0; c < nc; ++c) {
        float mb = Pm[row * 32 + c], lb = Pl[row * 32 + c];
        float nm = fmaxf(m, mb);
        l = l * __expf(m - nm) + lb * __expf(mb - nm);
        m = nm;
    }
    rl[row] = make_float2(m, 1.0f / l);
}

// ---------------- PV: O = softmax(S) * V, A staged as exp(S - m) in-register ----------------
// 128x128 tile, BK=32. A: reg-staged from S fp32 (exp+pack), LDS [128][40] padded.
// B: Vt bf16 via gload_lds, linear [128][32]. Kdim = (bx+1)*128 causal extent.
__global__ __launch_bounds__(256) void pv128(const float* __restrict__ S,
                                             const __hip_bfloat16* __restrict__ Vt,
                                             const float2* __restrict__ rl,
                                             float* __restrict__ Out) {
    const int bx = blockIdx.x, by = blockIdx.y, bz = blockIdx.z;
    const float* Sb = S + (size_t)bz * NSEQ * NSEQ;
    const __hip_bfloat16* Bb = Vt + (size_t)bz * D_ * NSEQ;
    const int Kdim = (bx + 1) * 128;
    const int m0 = bx * 128, n0 = by * 128;

    __shared__ unsigned short Ap[128][40];     // 80B rows: 16B-aligned, ~2-way alias
    __shared__ __hip_bfloat16 Bs[128 * 32];

    const int tid = threadIdx.x;
    const int lane = tid & 63, wid = tid >> 6;
    const int wm = wid >> 1, wn = wid & 1;
    const int lr = lane & 15, lk = lane >> 4;

    // A-staging coords: thread t -> row r, 16-col half
    const int ar = tid >> 1, ah = (tid & 1) * 16;
    const float mrow = rl[bz * NSEQ + m0 + ar].x;
    const float* srow = Sb + (size_t)(m0 + ar) * NSEQ + ah;

    // B-staging (gload_lds): wave covers 32 rows of Bs
    const int srB = wid * 32 + (lane >> 2);
    const int scB = (lane & 3) * 8;
    const __hip_bfloat16* bptr = Bb + (size_t)(n0 + srB) * NSEQ + scB;
    char* BsW = (char*)Bs + wid * 2048;

    f32x4 acc[4][4] = {};

    for (int k0 = 0; k0 < Kdim; k0 += 32) {
        gload_lds16(bptr,                     BsW);
        gload_lds16(bptr + (size_t)16 * NSEQ, BsW + 1024);
        bptr += 32;
        // A: read 16 fp32, exp, pack bf16, 2x ds_write_b128
        float4 v0 = *reinterpret_cast<const float4*>(srow + k0 + 0);
        float4 v1 = *reinterpret_cast<const float4*>(srow + k0 + 4);
        float4 v2 = *reinterpret_cast<const float4*>(srow + k0 + 8);
        float4 v3 = *reinterpret_cast<const float4*>(srow + k0 + 12);
        union { unsigned short u[8]; uint4 v; } p0, p1;
        p0.u[0] = f2bf(__expf(v0.x - mrow)); p0.u[1] = f2bf(__expf(v0.y - mrow));
        p0.u[2] = f2bf(__expf(v0.z - mrow)); p0.u[3] = f2bf(__expf(v0.w - mrow));
        p0.u[4] = f2bf(__expf(v1.x - mrow)); p0.u[5] = f2bf(__expf(v1.y - mrow));
        p0.u[6] = f2bf(__expf(v1.z - mrow)); p0.u[7] = f2bf(__expf(v1.w - mrow));
        p1.u[0] = f2bf(__expf(v2.x - mrow)); p1.u[1] = f2bf(__expf(v2.y - mrow));
        p1.u[2] = f2bf(__expf(v2.z - mrow)); p1.u[3] = f2bf(__expf(v2.w - mrow));
        p1.u[4] = f2bf(__expf(v3.x - mrow)); p1.u[5] = f2bf(__expf(v3.y - mrow));
        p1.u[6] = f2bf(__expf(v3.z - mrow)); p1.u[7] = f2bf(__expf(v3.w - mrow));
        *reinterpret_cast<uint4*>(&Ap[ar][ah + 0]) = p0.v;
        *reinterpret_cast<uint4*>(&Ap[ar][ah + 8]) = p1.v;
        __syncthreads();

        bf16x8 af[4], bfr[4];
#pragma unroll
        for (int m = 0; m < 4; ++m)
            af[m] = *reinterpret_cast<const bf16x8*>(&Ap[wm * 64 + m * 16 + lr][lk * 8]);
#pragma unroll
        for (int n = 0; n < 4; ++n)
            bfr[n] = *reinterpret_cast<const bf16x8*>(&Bs[(wn * 64 + n * 16 + lr) * 32 + lk * 8]);
#pragma unroll
        for (int m = 0; m < 4; ++m)
#pragma unroll
            for (int n = 0; n < 4; ++n)
                acc[m][n] = __builtin_amdgcn_mfma_f32_16x16x32_bf16(af[m], bfr[n], acc[m][n], 0, 0, 0);
        __syncthreads();
    }

    float* O = Out + (size_t)bz * NSEQ * D_;
#pragma unroll
    for (int m = 0; m < 4; ++m)
#pragma unroll
        for (int n = 0; n < 4; ++n) {
            const int rbase = m0 + wm * 64 + m * 16 + lk * 4;
            const int cbase = n0 + wn * 64 + n * 16 + lr;
#pragma unroll
            for (int j = 0; j < 4; ++j)
                O[(size_t)(rbase + j) * D_ + cbase] =
                    acc[m][n][j] * rl[bz * NSEQ + rbase + j].y;
        }
}

extern "C" void kernel_launch(void* const* d_in, const int* in_sizes, int n_in,
                              void* d_out, int out_size, void* d_ws, size_t ws_size,
                              hipStream_t stream) {
    const float* x  = (const float*)d_in[0];
    const float* Wq = (const float*)d_in[1];
    const float* Wk = (const float*)d_in[2];
    const float* Wv = (const float*)d_in[3];

    char* ws = (char*)d_ws;
    float*          S    = (float*)(ws);                        // 64 MiB
    __hip_bfloat16* Xb   = (__hip_bfloat16*)(ws + 67108864);    // 16 MiB (dead after QKV)
    __hip_bfloat16* Q    = (__hip_bfloat16*)(ws + 83886080);    // 16 MiB
    __hip_bfloat16* K    = (__hip_bfloat16*)(ws + 100663296);   // 16 MiB
    __hip_bfloat16* Vt   = (__hip_bfloat16*)(ws + 117440512);   // 16 MiB
    __hip_bfloat16* Wt   = (__hip_bfloat16*)(ws + 134217728);   // 6 MiB
    // partial-stat buffers overlay the Xb region (only needed after QKV consumed Xb)
    float*  Pm = (float*)(ws + 67108864);                       // 1 MiB
    float*  Pl = (float*)(ws + 68157440);                       // 1 MiB
    float2* rl = (float2*)(ws + 69206016);                      // 64 KiB

    cvt_x<<<8192, 256, 0, stream>>>(x, Xb);
    wt_kernel<<<dim3(32, 32, 3), 256, 0, stream>>>(Wq, Wk, Wv, Wt);

    // fused QKV: [8192,1024] x [3072,1024]^T
    gemm128<0><<<dim3(64, 24, 1), 256, 0, stream>>>(Xb, 1024, Wt, 1024, Q, K, Vt);

    // scores + partial softmax stats
    gemm128<2><<<dim3(16, 16, 4), 256, 0, stream>>>(Q, 1024, K, 1024, S, Pm, Pl);
    merge_stats<<<32, 256, 0, stream>>>(Pm, Pl, rl);
    // PV with exp-on-stage
    pv128<<<dim3(16, 8, 4), 256, 0, stream>>>(S, Vt, rl, (float*)d_out);
}

// Round 5
// 202.422 us; speedup vs baseline: 1.0845x; 1.0845x over previous
//
#include <hip/hip_runtime.h>
#include <hip/hip_bf16.h>
#include <stdint.h>

#define D_ 1024
#define NSEQ 2048

typedef __attribute__((ext_vector_type(8))) short bf16x8;
typedef __attribute__((ext_vector_type(4))) float f32x4;

static __device__ __forceinline__ unsigned short f2bf(float x) {
    union { __hip_bfloat16 h; unsigned short u; } cv;
    cv.h = __float2bfloat16(x);
    return cv.u;
}

// async global->LDS, 16B per lane. LDS dest = wave-uniform base + lane*16 (HW).
static __device__ __forceinline__ void gload_lds16(const void* g, void* l) {
    __builtin_amdgcn_global_load_lds(
        (const __attribute__((address_space(1))) unsigned int*)(uintptr_t)g,
        (__attribute__((address_space(3))) unsigned int*)(uintptr_t)l, 16, 0, 0);
}

// ---------------- x fp32 -> bf16 ----------------
__global__ __launch_bounds__(256) void cvt_x(const float* __restrict__ x,
                                             __hip_bfloat16* __restrict__ xb) {
    int i = blockIdx.x * 256 + threadIdx.x;
    float4 v = reinterpret_cast<const float4*>(x)[i];
    ushort4 o;
    o.x = f2bf(v.x); o.y = f2bf(v.y); o.z = f2bf(v.z); o.w = f2bf(v.w);
    reinterpret_cast<ushort4*>(xb)[i] = o;
}

// ---------------- W [d][e] fp32 -> Wt [e][d] bf16 (3 weights stacked -> [3072][1024]) ----------------
__global__ __launch_bounds__(256) void wt_kernel(const float* __restrict__ Wq,
                                                 const float* __restrict__ Wk,
                                                 const float* __restrict__ Wv,
                                                 __hip_bfloat16* __restrict__ Wt) {
    const float* W = (blockIdx.z == 0) ? Wq : (blockIdx.z == 1) ? Wk : Wv;
    unsigned short* O = (unsigned short*)(Wt + (size_t)blockIdx.z * D_ * D_);
    __shared__ float tile[32][33];
    int r0 = blockIdx.y * 32, c0 = blockIdx.x * 32;
    int t = threadIdx.x;
    int r = t >> 3, c4 = (t & 7) * 4;
    float4 v = *reinterpret_cast<const float4*>(&W[(size_t)(r0 + r) * D_ + c0 + c4]);
    tile[r][c4 + 0] = v.x; tile[r][c4 + 1] = v.y;
    tile[r][c4 + 2] = v.z; tile[r][c4 + 3] = v.w;
    __syncthreads();
    int er = t >> 3, dc = (t & 7) * 4;
    ushort4 pk;
    pk.x = f2bf(tile[dc + 0][er]); pk.y = f2bf(tile[dc + 1][er]);
    pk.z = f2bf(tile[dc + 2][er]); pk.w = f2bf(tile[dc + 3][er]);
    *reinterpret_cast<ushort4*>(&O[(size_t)(c0 + er) * D_ + r0 + dc]) = pk;
}

// ---------------- NT GEMM, 128x128 tile, BK=32, 4 waves (2x2), 4x4 frags/wave ----------------
// MODE 0: fused QKV epilogue (o0=Q, o1=K row-major; o2=Vt transposed per batch)
// MODE 2: scores: S fp32 *1/32, causal mask, skip by>bx; per-(row, 64-col-slice)
//         partial softmax stats (max, sum-exp) -> o1=Pm, o2=Pl; S in o0
// MODE 3: PV: A = P bf16 (lda 4096 over S region), Kdim=(bx+1)*128, out fp32 * rl[q].y
template <int MODE>
__global__ __launch_bounds__(256) void gemm128(const __hip_bfloat16* __restrict__ A, int lda,
                                               const __hip_bfloat16* __restrict__ Bt, int ldb,
                                               void* __restrict__ o0, void* __restrict__ o1,
                                               void* __restrict__ o2,
                                               const float2* __restrict__ rl) {
    const int bx = blockIdx.x, by = blockIdx.y, bz = blockIdx.z;
    if (MODE == 2 && by > bx) return;    // fully masked tile, never read downstream

    const __hip_bfloat16* Ab = A;
    const __hip_bfloat16* Bb = Bt;
    int Kdim = 1024;
    if (MODE == 2) { Ab += (size_t)bz * NSEQ * D_;  Bb += (size_t)bz * NSEQ * D_; }
    if (MODE == 3) { Ab += (size_t)bz * NSEQ * 4096; Bb += (size_t)bz * D_ * NSEQ; Kdim = (bx + 1) * 128; }

    const int m0 = bx * 128, n0 = by * 128;

    __shared__ __hip_bfloat16 As[128 * 32];   // linear [128][32], row stride 64B
    __shared__ __hip_bfloat16 Bs[128 * 32];

    const int tid = threadIdx.x;
    const int lane = tid & 63, wid = tid >> 6;
    const int wm = wid >> 1, wn = wid & 1;
    const int lr = lane & 15, lk = lane >> 4;

    const int srow = wid * 32 + (lane >> 2);
    const int scol = (lane & 3) * 8;
    const __hip_bfloat16* aptr = Ab + (size_t)(m0 + srow) * lda + scol;
    const __hip_bfloat16* bptr = Bb + (size_t)(n0 + srow) * ldb + scol;
    char* AsW = (char*)As + wid * 2048;
    char* BsW = (char*)Bs + wid * 2048;

    f32x4 acc[4][4] = {};

    for (int k0 = 0; k0 < Kdim; k0 += 32) {
        gload_lds16(aptr,                    AsW);
        gload_lds16(aptr + (size_t)16 * lda, AsW + 1024);
        gload_lds16(bptr,                    BsW);
        gload_lds16(bptr + (size_t)16 * ldb, BsW + 1024);
        aptr += 32; bptr += 32;
        __syncthreads();

        bf16x8 af[4], bfr[4];
#pragma unroll
        for (int m = 0; m < 4; ++m)
            af[m] = *reinterpret_cast<const bf16x8*>(&As[(wm * 64 + m * 16 + lr) * 32 + lk * 8]);
#pragma unroll
        for (int n = 0; n < 4; ++n)
            bfr[n] = *reinterpret_cast<const bf16x8*>(&Bs[(wn * 64 + n * 16 + lr) * 32 + lk * 8]);
#pragma unroll
        for (int m = 0; m < 4; ++m)
#pragma unroll
            for (int n = 0; n < 4; ++n)
                acc[m][n] = __builtin_amdgcn_mfma_f32_16x16x32_bf16(af[m], bfr[n], acc[m][n], 0, 0, 0);
        __syncthreads();
    }

    if (MODE == 0) {
#pragma unroll
        for (int m = 0; m < 4; ++m)
#pragma unroll
            for (int n = 0; n < 4; ++n) {
                const int rbase = m0 + wm * 64 + m * 16 + lk * 4;
                const int cbase = n0 + wn * 64 + n * 16 + lr;
                const int seg = cbase >> 10, e = cbase & 1023;
                if (seg < 2) {
                    unsigned short* C = (unsigned short*)(seg == 0 ? o0 : o1);
#pragma unroll
                    for (int j = 0; j < 4; ++j)
                        C[(size_t)(rbase + j) * D_ + e] = f2bf(acc[m][n][j]);
                } else {
                    unsigned short* Vt = (unsigned short*)o2;
                    const int b = rbase >> 11, nq = rbase & 2047;
                    ushort4 pk;
                    pk.x = f2bf(acc[m][n][0]); pk.y = f2bf(acc[m][n][1]);
                    pk.z = f2bf(acc[m][n][2]); pk.w = f2bf(acc[m][n][3]);
                    *reinterpret_cast<ushort4*>(&Vt[(((size_t)b << 10) + e) * NSEQ + nq]) = pk;
                }
            }
    } else if (MODE == 2) {
        // scale + mask into acc, store S fp32
        float* S = (float*)o0 + (size_t)bz * NSEQ * NSEQ;
#pragma unroll
        for (int m = 0; m < 4; ++m)
#pragma unroll
            for (int n = 0; n < 4; ++n) {
                const int rbase = m0 + wm * 64 + m * 16 + lk * 4;
                const int cbase = n0 + wn * 64 + n * 16 + lr;
#pragma unroll
                for (int j = 0; j < 4; ++j) {
                    float s = acc[m][n][j] * 0.03125f;    // 1/sqrt(1024)
                    if (cbase > rbase + j) s = -1e30f;
                    acc[m][n][j] = s;
                    S[(size_t)(rbase + j) * NSEQ + cbase] = s;
                }
            }
        // per-(row, 64-col slice) partial softmax stats; slice index = by*2 + wn
        float* Pm = (float*)o1;
        float* Pl = (float*)o2;
        const int pcol = by * 2 + wn;
#pragma unroll
        for (int m = 0; m < 4; ++m)
#pragma unroll
            for (int j = 0; j < 4; ++j) {
                float mx = fmaxf(fmaxf(acc[m][0][j], acc[m][1][j]),
                                 fmaxf(acc[m][2][j], acc[m][3][j]));
#pragma unroll
                for (int w = 1; w < 16; w <<= 1) mx = fmaxf(mx, __shfl_xor(mx, w, 64));
                float sm = __expf(acc[m][0][j] - mx) + __expf(acc[m][1][j] - mx) +
                           __expf(acc[m][2][j] - mx) + __expf(acc[m][3][j] - mx);
#pragma unroll
                for (int w = 1; w < 16; w <<= 1) sm += __shfl_xor(sm, w, 64);
                if (lr == 0) {
                    const int row = bz * NSEQ + m0 + wm * 64 + m * 16 + lk * 4 + j;
                    Pm[row * 32 + pcol] = mx;
                    Pl[row * 32 + pcol] = sm;
                }
            }
    } else {
        float* O = (float*)o0 + (size_t)bz * NSEQ * D_;
#pragma unroll
        for (int m = 0; m < 4; ++m)
#pragma unroll
            for (int n = 0; n < 4; ++n) {
                const int rbase = m0 + wm * 64 + m * 16 + lk * 4;
                const int cbase = n0 + wn * 64 + n * 16 + lr;
#pragma unroll
                for (int j = 0; j < 4; ++j)
                    O[(size_t)(rbase + j) * D_ + cbase] =
                        acc[m][n][j] * rl[bz * NSEQ + rbase + j].y;
            }
    }
}

// ---------------- merge partial stats + one-pass exp: P bf16 = exp(S - m), in place ----------------
__global__ __launch_bounds__(256) void softmax_finish(float* __restrict__ S,
                                                      const float* __restrict__ Pm,
                                                      const float* __restrict__ Pl,
                                                      float2* __restrict__ rl) {
    const int lane = threadIdx.x & 63;
    const int row = blockIdx.x * 4 + (threadIdx.x >> 6);   // 0..8191
    const int q = row & 2047;
    const int nb = (q >> 7) + 1;      // causal extent in 128-blocks
    const int nc = nb * 2;            // 64-col slices, <= 32

    // merge partials across the wave (lane = slice index)
    float mb = (lane < nc) ? Pm[row * 32 + lane] : -3e38f;
    float m = mb;
#pragma unroll
    for (int off = 32; off > 0; off >>= 1) m = fmaxf(m, __shfl_xor(m, off, 64));
    float lb = (lane < nc) ? Pl[row * 32 + lane] * __expf(mb - m) : 0.f;
#pragma unroll
    for (int off = 32; off > 0; off >>= 1) lb += __shfl_xor(lb, off, 64);
    if (lane == 0) rl[row] = make_float2(m, 1.0f / lb);

    // one-pass exp transform: fp32 reads, bf16 writes trail (single wave owns the row)
    float* srow = S + (size_t)row * NSEQ;
    unsigned short* prow = (unsigned short*)srow;
    const int L = nb << 7;
    for (int k = lane * 4; k < L; k += 256) {
        float4 v = *reinterpret_cast<const float4*>(srow + k);
        ushort4 pk;
        pk.x = f2bf(__expf(v.x - m)); pk.y = f2bf(__expf(v.y - m));
        pk.z = f2bf(__expf(v.z - m)); pk.w = f2bf(__expf(v.w - m));
        *reinterpret_cast<ushort4*>(prow + k) = pk;
    }
}

extern "C" void kernel_launch(void* const* d_in, const int* in_sizes, int n_in,
                              void* d_out, int out_size, void* d_ws, size_t ws_size,
                              hipStream_t stream) {
    const float* x  = (const float*)d_in[0];
    const float* Wq = (const float*)d_in[1];
    const float* Wk = (const float*)d_in[2];
    const float* Wv = (const float*)d_in[3];

    char* ws = (char*)d_ws;
    float*          S    = (float*)(ws);                        // 64 MiB
    __hip_bfloat16* Xb   = (__hip_bfloat16*)(ws + 67108864);    // 16 MiB (dead after QKV)
    __hip_bfloat16* Q    = (__hip_bfloat16*)(ws + 83886080);    // 16 MiB
    __hip_bfloat16* K    = (__hip_bfloat16*)(ws + 100663296);   // 16 MiB
    __hip_bfloat16* Vt   = (__hip_bfloat16*)(ws + 117440512);   // 16 MiB
    __hip_bfloat16* Wt   = (__hip_bfloat16*)(ws + 134217728);   // 6 MiB
    // partial-stat buffers overlay the Xb region (only needed after QKV consumed Xb)
    float*  Pm = (float*)(ws + 67108864);                       // 1 MiB
    float*  Pl = (float*)(ws + 68157440);                       // 1 MiB
    float2* rl = (float2*)(ws + 69206016);                      // 64 KiB

    cvt_x<<<8192, 256, 0, stream>>>(x, Xb);
    wt_kernel<<<dim3(32, 32, 3), 256, 0, stream>>>(Wq, Wk, Wv, Wt);

    // fused QKV: [8192,1024] x [3072,1024]^T
    gemm128<0><<<dim3(64, 24, 1), 256, 0, stream>>>(Xb, 1024, Wt, 1024, Q, K, Vt, nullptr);

    // scores + partial softmax stats
    gemm128<2><<<dim3(16, 16, 4), 256, 0, stream>>>(Q, 1024, K, 1024, S, Pm, Pl, nullptr);
    // merge stats + exp transform (S fp32 -> P bf16 in place)
    softmax_finish<<<2048, 256, 0, stream>>>(S, Pm, Pl, rl);
    // PV
    gemm128<3><<<dim3(16, 8, 4), 256, 0, stream>>>((const __hip_bfloat16*)S, 4096, Vt, 2048,
                                                   d_out, nullptr, nullptr, rl);
}

// Round 6
// 175.380 us; speedup vs baseline: 1.2517x; 1.1542x over previous
//
#include <hip/hip_runtime.h>
#include <hip/hip_bf16.h>
#include <stdint.h>

#define D_ 1024
#define NSEQ 2048

typedef __attribute__((ext_vector_type(8))) short bf16x8;
typedef __attribute__((ext_vector_type(4))) float f32x4;

static __device__ __forceinline__ unsigned short f2bf(float x) {
    union { __hip_bfloat16 h; unsigned short u; } cv;
    cv.h = __float2bfloat16(x);
    return cv.u;
}

// async global->LDS, 16B per lane. LDS dest = wave-uniform base + lane*16 (HW).
static __device__ __forceinline__ void gload_lds16(const void* g, void* l) {
    __builtin_amdgcn_global_load_lds(
        (const __attribute__((address_space(1))) unsigned int*)(uintptr_t)g,
        (__attribute__((address_space(3))) unsigned int*)(uintptr_t)l, 16, 0, 0);
}

// ---------------- x fp32 -> bf16 ----------------
__global__ __launch_bounds__(256) void cvt_x(const float* __restrict__ x,
                                             __hip_bfloat16* __restrict__ xb) {
    int i = blockIdx.x * 256 + threadIdx.x;
    float4 v = reinterpret_cast<const float4*>(x)[i];
    ushort4 o;
    o.x = f2bf(v.x); o.y = f2bf(v.y); o.z = f2bf(v.z); o.w = f2bf(v.w);
    reinterpret_cast<ushort4*>(xb)[i] = o;
}

// ---------------- W [d][e] fp32 -> Wt [e][d] bf16 (3 weights stacked -> [3072][1024]) ----------------
__global__ __launch_bounds__(256) void wt_kernel(const float* __restrict__ Wq,
                                                 const float* __restrict__ Wk,
                                                 const float* __restrict__ Wv,
                                                 __hip_bfloat16* __restrict__ Wt) {
    const float* W = (blockIdx.z == 0) ? Wq : (blockIdx.z == 1) ? Wk : Wv;
    unsigned short* O = (unsigned short*)(Wt + (size_t)blockIdx.z * D_ * D_);
    __shared__ float tile[32][33];
    int r0 = blockIdx.y * 32, c0 = blockIdx.x * 32;
    int t = threadIdx.x;
    int r = t >> 3, c4 = (t & 7) * 4;
    float4 v = *reinterpret_cast<const float4*>(&W[(size_t)(r0 + r) * D_ + c0 + c4]);
    tile[r][c4 + 0] = v.x; tile[r][c4 + 1] = v.y;
    tile[r][c4 + 2] = v.z; tile[r][c4 + 3] = v.w;
    __syncthreads();
    int er = t >> 3, dc = (t & 7) * 4;
    ushort4 pk;
    pk.x = f2bf(tile[dc + 0][er]); pk.y = f2bf(tile[dc + 1][er]);
    pk.z = f2bf(tile[dc + 2][er]); pk.w = f2bf(tile[dc + 3][er]);
    *reinterpret_cast<ushort4*>(&O[(size_t)(c0 + er) * D_ + r0 + dc]) = pk;
}

// ---------------- NT GEMM, 128x128 tile, BK=32, 4 waves (2x2), 4x4 frags/wave ----------------
// MODE 0: fused QKV epilogue (o0=Q, o1=K row-major; o2=Vt transposed per batch); 2-D grid
// MODE 2: scores; FLAT grid of 544 = 136 lower-tri tiles x 4 batches (bz in low bits)
// MODE 3: PV;     FLAT grid of 512 with anti-correlated Kdim pairing (uniform 68 k-steps/CU)
template <int MODE>
__global__ __launch_bounds__(256) void gemm128(const __hip_bfloat16* __restrict__ A, int lda,
                                               const __hip_bfloat16* __restrict__ Bt, int ldb,
                                               void* __restrict__ o0, void* __restrict__ o1,
                                               void* __restrict__ o2,
                                               const float2* __restrict__ rl) {
    int bx, by, bz;
    if (MODE == 0) {
        bx = blockIdx.x; by = blockIdx.y; bz = 0;
    } else if (MODE == 2) {
        const int fid = blockIdx.x;            // 0..543
        bz = fid & 3;
        const int t = fid >> 2;                // 0..135 triangular index
        bx = (int)((sqrtf(8.0f * t + 1.0f) - 1.0f) * 0.5f);
        while ((bx + 1) * (bx + 2) / 2 <= t) ++bx;
        while (bx * (bx + 1) / 2 > t) --bx;
        by = t - bx * (bx + 1) / 2;            // by <= bx guaranteed
    } else {
        const int fid = blockIdx.x;            // 0..511
        const int bxr = fid & 15;
        bx = (fid & 256) ? 15 - bxr : bxr;     // CU c gets bx and 15-bx -> uniform load
        bz = (fid >> 4) & 3;
        by = fid >> 6;                         // 0..7
    }

    const __hip_bfloat16* Ab = A;
    const __hip_bfloat16* Bb = Bt;
    int Kdim = 1024;
    if (MODE == 2) { Ab += (size_t)bz * NSEQ * D_;  Bb += (size_t)bz * NSEQ * D_; }
    if (MODE == 3) { Ab += (size_t)bz * NSEQ * 4096; Bb += (size_t)bz * D_ * NSEQ; Kdim = (bx + 1) * 128; }

    const int m0 = bx * 128, n0 = by * 128;

    __shared__ __hip_bfloat16 As[128 * 32];   // linear [128][32], row stride 64B
    __shared__ __hip_bfloat16 Bs[128 * 32];

    const int tid = threadIdx.x;
    const int lane = tid & 63, wid = tid >> 6;
    const int wm = wid >> 1, wn = wid & 1;
    const int lr = lane & 15, lk = lane >> 4;

    const int srow = wid * 32 + (lane >> 2);
    const int scol = (lane & 3) * 8;
    const __hip_bfloat16* aptr = Ab + (size_t)(m0 + srow) * lda + scol;
    const __hip_bfloat16* bptr = Bb + (size_t)(n0 + srow) * ldb + scol;
    char* AsW = (char*)As + wid * 2048;
    char* BsW = (char*)Bs + wid * 2048;

    f32x4 acc[4][4] = {};

    for (int k0 = 0; k0 < Kdim; k0 += 32) {
        gload_lds16(aptr,                    AsW);
        gload_lds16(aptr + (size_t)16 * lda, AsW + 1024);
        gload_lds16(bptr,                    BsW);
        gload_lds16(bptr + (size_t)16 * ldb, BsW + 1024);
        aptr += 32; bptr += 32;
        __syncthreads();

        bf16x8 af[4], bfr[4];
#pragma unroll
        for (int m = 0; m < 4; ++m)
            af[m] = *reinterpret_cast<const bf16x8*>(&As[(wm * 64 + m * 16 + lr) * 32 + lk * 8]);
#pragma unroll
        for (int n = 0; n < 4; ++n)
            bfr[n] = *reinterpret_cast<const bf16x8*>(&Bs[(wn * 64 + n * 16 + lr) * 32 + lk * 8]);
#pragma unroll
        for (int m = 0; m < 4; ++m)
#pragma unroll
            for (int n = 0; n < 4; ++n)
                acc[m][n] = __builtin_amdgcn_mfma_f32_16x16x32_bf16(af[m], bfr[n], acc[m][n], 0, 0, 0);
        __syncthreads();
    }

    if (MODE == 0) {
#pragma unroll
        for (int m = 0; m < 4; ++m)
#pragma unroll
            for (int n = 0; n < 4; ++n) {
                const int rbase = m0 + wm * 64 + m * 16 + lk * 4;
                const int cbase = n0 + wn * 64 + n * 16 + lr;
                const int seg = cbase >> 10, e = cbase & 1023;
                if (seg < 2) {
                    unsigned short* C = (unsigned short*)(seg == 0 ? o0 : o1);
#pragma unroll
                    for (int j = 0; j < 4; ++j)
                        C[(size_t)(rbase + j) * D_ + e] = f2bf(acc[m][n][j]);
                } else {
                    unsigned short* Vt = (unsigned short*)o2;
                    const int b = rbase >> 11, nq = rbase & 2047;
                    ushort4 pk;
                    pk.x = f2bf(acc[m][n][0]); pk.y = f2bf(acc[m][n][1]);
                    pk.z = f2bf(acc[m][n][2]); pk.w = f2bf(acc[m][n][3]);
                    *reinterpret_cast<ushort4*>(&Vt[(((size_t)b << 10) + e) * NSEQ + nq]) = pk;
                }
            }
    } else if (MODE == 2) {
        // scale + mask into acc, store S fp32
        float* S = (float*)o0 + (size_t)bz * NSEQ * NSEQ;
#pragma unroll
        for (int m = 0; m < 4; ++m)
#pragma unroll
            for (int n = 0; n < 4; ++n) {
                const int rbase = m0 + wm * 64 + m * 16 + lk * 4;
                const int cbase = n0 + wn * 64 + n * 16 + lr;
#pragma unroll
                for (int j = 0; j < 4; ++j) {
                    float s = acc[m][n][j] * 0.03125f;    // 1/sqrt(1024)
                    if (cbase > rbase + j) s = -1e30f;
                    acc[m][n][j] = s;
                    S[(size_t)(rbase + j) * NSEQ + cbase] = s;
                }
            }
        // per-(row, 64-col slice) partial softmax stats; slice index = by*2 + wn
        float* Pm = (float*)o1;
        float* Pl = (float*)o2;
        const int pcol = by * 2 + wn;
#pragma unroll
        for (int m = 0; m < 4; ++m)
#pragma unroll
            for (int j = 0; j < 4; ++j) {
                float mx = fmaxf(fmaxf(acc[m][0][j], acc[m][1][j]),
                                 fmaxf(acc[m][2][j], acc[m][3][j]));
#pragma unroll
                for (int w = 1; w < 16; w <<= 1) mx = fmaxf(mx, __shfl_xor(mx, w, 64));
                float sm = __expf(acc[m][0][j] - mx) + __expf(acc[m][1][j] - mx) +
                           __expf(acc[m][2][j] - mx) + __expf(acc[m][3][j] - mx);
#pragma unroll
                for (int w = 1; w < 16; w <<= 1) sm += __shfl_xor(sm, w, 64);
                if (lr == 0) {
                    const int row = bz * NSEQ + m0 + wm * 64 + m * 16 + lk * 4 + j;
                    Pm[row * 32 + pcol] = mx;
                    Pl[row * 32 + pcol] = sm;
                }
            }
    } else {
        float* O = (float*)o0 + (size_t)bz * NSEQ * D_;
#pragma unroll
        for (int m = 0; m < 4; ++m)
#pragma unroll
            for (int n = 0; n < 4; ++n) {
                const int rbase = m0 + wm * 64 + m * 16 + lk * 4;
                const int cbase = n0 + wn * 64 + n * 16 + lr;
#pragma unroll
                for (int j = 0; j < 4; ++j)
                    O[(size_t)(rbase + j) * D_ + cbase] =
                        acc[m][n][j] * rl[bz * NSEQ + rbase + j].y;
            }
    }
}

// ---------------- merge partial stats + one-pass exp: P bf16 = exp(S - m), in place ----------------
__global__ __launch_bounds__(256) void softmax_finish(float* __restrict__ S,
                                                      const float* __restrict__ Pm,
                                                      const float* __restrict__ Pl,
                                                      float2* __restrict__ rl) {
    const int lane = threadIdx.x & 63;
    const int row = blockIdx.x * 4 + (threadIdx.x >> 6);   // 0..8191
    const int q = row & 2047;
    const int nb = (q >> 7) + 1;      // causal extent in 128-blocks
    const int nc = nb * 2;            // 64-col slices, <= 32

    // merge partials across the wave (lane = slice index)
    float mb = (lane < nc) ? Pm[row * 32 + lane] : -3e38f;
    float m = mb;
#pragma unroll
    for (int off = 32; off > 0; off >>= 1) m = fmaxf(m, __shfl_xor(m, off, 64));
    float lb = (lane < nc) ? Pl[row * 32 + lane] * __expf(mb - m) : 0.f;
#pragma unroll
    for (int off = 32; off > 0; off >>= 1) lb += __shfl_xor(lb, off, 64);
    if (lane == 0) rl[row] = make_float2(m, 1.0f / lb);

    // one-pass exp transform: fp32 reads, bf16 writes trail (single wave owns the row)
    float* srow = S + (size_t)row * NSEQ;
    unsigned short* prow = (unsigned short*)srow;
    const int L = nb << 7;
    for (int k = lane * 4; k < L; k += 256) {
        float4 v = *reinterpret_cast<const float4*>(srow + k);
        ushort4 pk;
        pk.x = f2bf(__expf(v.x - m)); pk.y = f2bf(__expf(v.y - m));
        pk.z = f2bf(__expf(v.z - m)); pk.w = f2bf(__expf(v.w - m));
        *reinterpret_cast<ushort4*>(prow + k) = pk;
    }
}

extern "C" void kernel_launch(void* const* d_in, const int* in_sizes, int n_in,
                              void* d_out, int out_size, void* d_ws, size_t ws_size,
                              hipStream_t stream) {
    const float* x  = (const float*)d_in[0];
    const float* Wq = (const float*)d_in[1];
    const float* Wk = (const float*)d_in[2];
    const float* Wv = (const float*)d_in[3];

    char* ws = (char*)d_ws;
    float*          S    = (float*)(ws);                        // 64 MiB
    __hip_bfloat16* Xb   = (__hip_bfloat16*)(ws + 67108864);    // 16 MiB (dead after QKV)
    __hip_bfloat16* Q    = (__hip_bfloat16*)(ws + 83886080);    // 16 MiB
    __hip_bfloat16* K    = (__hip_bfloat16*)(ws + 100663296);   // 16 MiB
    __hip_bfloat16* Vt   = (__hip_bfloat16*)(ws + 117440512);   // 16 MiB
    __hip_bfloat16* Wt   = (__hip_bfloat16*)(ws + 134217728);   // 6 MiB
    // partial-stat buffers overlay the Xb region (only needed after QKV consumed Xb)
    float*  Pm = (float*)(ws + 67108864);                       // 1 MiB
    float*  Pl = (float*)(ws + 68157440);                       // 1 MiB
    float2* rl = (float2*)(ws + 69206016);                      // 64 KiB

    cvt_x<<<8192, 256, 0, stream>>>(x, Xb);
    wt_kernel<<<dim3(32, 32, 3), 256, 0, stream>>>(Wq, Wk, Wv, Wt);

    // fused QKV: [8192,1024] x [3072,1024]^T
    gemm128<0><<<dim3(64, 24, 1), 256, 0, stream>>>(Xb, 1024, Wt, 1024, Q, K, Vt, nullptr);

    // scores + partial softmax stats (flat lower-triangle enumeration: 136 tiles x 4 batches)
    gemm128<2><<<dim3(544), 256, 0, stream>>>(Q, 1024, K, 1024, S, Pm, Pl, nullptr);
    // merge stats + exp transform (S fp32 -> P bf16 in place)
    softmax_finish<<<2048, 256, 0, stream>>>(S, Pm, Pl, rl);
    // PV (flat grid, anti-correlated Kdim pairing)
    gemm128<3><<<dim3(512), 256, 0, stream>>>((const __hip_bfloat16*)S, 4096, Vt, 2048,
                                              d_out, nullptr, nullptr, rl);
}

// Round 7
// 169.711 us; speedup vs baseline: 1.2935x; 1.0334x over previous
//
#include <hip/hip_runtime.h>
#include <hip/hip_bf16.h>
#include <stdint.h>

#define D_ 1024
#define NSEQ 2048

typedef __attribute__((ext_vector_type(8))) short bf16x8;
typedef __attribute__((ext_vector_type(4))) float f32x4;

static __device__ __forceinline__ unsigned short f2bf(float x) {
    union { __hip_bfloat16 h; unsigned short u; } cv;
    cv.h = __float2bfloat16(x);
    return cv.u;
}
static __device__ __forceinline__ float bf2f(unsigned short u) {
    union { float f; unsigned int i; } cv;
    cv.i = ((unsigned int)u) << 16;
    return cv.f;
}

// async global->LDS, 16B per lane. LDS dest = wave-uniform base + lane*16 (HW).
static __device__ __forceinline__ void gload_lds16(const void* g, void* l) {
    __builtin_amdgcn_global_load_lds(
        (const __attribute__((address_space(1))) unsigned int*)(uintptr_t)g,
        (__attribute__((address_space(3))) unsigned int*)(uintptr_t)l, 16, 0, 0);
}

// ---------------- x fp32 -> bf16 ----------------
__global__ __launch_bounds__(256) void cvt_x(const float* __restrict__ x,
                                             __hip_bfloat16* __restrict__ xb) {
    int i = blockIdx.x * 256 + threadIdx.x;
    float4 v = reinterpret_cast<const float4*>(x)[i];
    ushort4 o;
    o.x = f2bf(v.x); o.y = f2bf(v.y); o.z = f2bf(v.z); o.w = f2bf(v.w);
    reinterpret_cast<ushort4*>(xb)[i] = o;
}

// ---------------- W [d][e] fp32 -> Wt [e][d] bf16 (3 weights stacked -> [3072][1024]) ----------------
__global__ __launch_bounds__(256) void wt_kernel(const float* __restrict__ Wq,
                                                 const float* __restrict__ Wk,
                                                 const float* __restrict__ Wv,
                                                 __hip_bfloat16* __restrict__ Wt) {
    const float* W = (blockIdx.z == 0) ? Wq : (blockIdx.z == 1) ? Wk : Wv;
    unsigned short* O = (unsigned short*)(Wt + (size_t)blockIdx.z * D_ * D_);
    __shared__ float tile[32][33];
    int r0 = blockIdx.y * 32, c0 = blockIdx.x * 32;
    int t = threadIdx.x;
    int r = t >> 3, c4 = (t & 7) * 4;
    float4 v = *reinterpret_cast<const float4*>(&W[(size_t)(r0 + r) * D_ + c0 + c4]);
    tile[r][c4 + 0] = v.x; tile[r][c4 + 1] = v.y;
    tile[r][c4 + 2] = v.z; tile[r][c4 + 3] = v.w;
    __syncthreads();
    int er = t >> 3, dc = (t & 7) * 4;
    ushort4 pk;
    pk.x = f2bf(tile[dc + 0][er]); pk.y = f2bf(tile[dc + 1][er]);
    pk.z = f2bf(tile[dc + 2][er]); pk.w = f2bf(tile[dc + 3][er]);
    *reinterpret_cast<ushort4*>(&O[(size_t)(c0 + er) * D_ + r0 + dc]) = pk;
}

// ---------------- NT GEMM, 128x128 tile, BK=64, 4 waves (2x2), 4x4 frags/wave ----------------
// LDS [128][64] bf16 (128B rows) with 16B-slot XOR swizzle: linear LDS position
// (row, s) holds global (row, s ^ (row&7)) -- staged via pre-swizzled global source
// (gload_lds dest stays linear), read back with the same XOR. Residual 2-way alias = free.
// MODE 0: fused QKV epilogue (o0=Q, o1=K row-major; o2=Vt transposed per batch); 2-D grid
// MODE 2: scores -> S bf16 *1/32 + causal mask + per-(row,64col) partial stats;
//         FLAT grid of 544 = 136 lower-tri tiles x 4 batches
// MODE 3: PV; FLAT grid of 512 with anti-correlated Kdim pairing
template <int MODE>
__global__ __launch_bounds__(256) void gemm128(const __hip_bfloat16* __restrict__ A, int lda,
                                               const __hip_bfloat16* __restrict__ Bt, int ldb,
                                               void* __restrict__ o0, void* __restrict__ o1,
                                               void* __restrict__ o2,
                                               const float2* __restrict__ rl) {
    int bx, by, bz;
    if (MODE == 0) {
        bx = blockIdx.x; by = blockIdx.y; bz = 0;
    } else if (MODE == 2) {
        const int fid = blockIdx.x;            // 0..543
        bz = fid & 3;
        const int t = fid >> 2;                // 0..135 triangular index
        bx = (int)((sqrtf(8.0f * t + 1.0f) - 1.0f) * 0.5f);
        while ((bx + 1) * (bx + 2) / 2 <= t) ++bx;
        while (bx * (bx + 1) / 2 > t) --bx;
        by = t - bx * (bx + 1) / 2;            // by <= bx guaranteed
    } else {
        const int fid = blockIdx.x;            // 0..511
        const int bxr = fid & 15;
        bx = (fid & 256) ? 15 - bxr : bxr;     // CU c gets bx and 15-bx -> uniform load
        bz = (fid >> 4) & 3;
        by = fid >> 6;                         // 0..7
    }

    const __hip_bfloat16* Ab = A;
    const __hip_bfloat16* Bb = Bt;
    int Kdim = 1024;
    if (MODE == 2) { Ab += (size_t)bz * NSEQ * lda; Bb += (size_t)bz * NSEQ * ldb; }
    if (MODE == 3) { Ab += (size_t)bz * NSEQ * lda; Bb += (size_t)bz * D_ * ldb; Kdim = (bx + 1) * 128; }

    const int m0 = bx * 128, n0 = by * 128;

    __shared__ __hip_bfloat16 As[128 * 64];   // [128][64], 128B rows, swizzled content
    __shared__ __hip_bfloat16 Bs[128 * 64];

    const int tid = threadIdx.x;
    const int lane = tid & 63, wid = tid >> 6;
    const int wm = wid >> 1, wn = wid & 1;
    const int lr = lane & 15, lk = lane >> 4;

    // staging: 4 rounds per operand; round r: chunk = r*256+tid; row=chunk>>3, slot=chunk&7
    // global source col = (slot ^ (row&7))*8 elems -> LDS gets the swizzled layout linearly
    const __hip_bfloat16* asrc[4];
    const __hip_bfloat16* bsrc[4];
#pragma unroll
    for (int r = 0; r < 4; ++r) {
        const int chunk = r * 256 + tid;
        const int row = chunk >> 3, slot = chunk & 7;
        const int col = ((slot ^ (row & 7)) * 8);
        asrc[r] = Ab + (size_t)(m0 + row) * lda + col;
        bsrc[r] = Bb + (size_t)(n0 + row) * ldb + col;
    }

    // read-side: frag (row, c8=kk*4+lk) lives at slot c8 ^ (row&7); row&7 == lr&7 here
    const int sw = lr & 7;
    const int slotA0 = (lk ^ sw) * 16, slotA1 = ((4 + lk) ^ sw) * 16;

    f32x4 acc[4][4] = {};

    for (int k0 = 0; k0 < Kdim; k0 += 64) {
#pragma unroll
        for (int r = 0; r < 4; ++r) {
            gload_lds16(asrc[r], (char*)As + r * 4096 + wid * 1024);
            gload_lds16(bsrc[r], (char*)Bs + r * 4096 + wid * 1024);
            asrc[r] += 64; bsrc[r] += 64;
        }
        __syncthreads();   // drains vmcnt (loads landed) + barrier

        bf16x8 af0[4], bf0[4], af1[4], bf1[4];
#pragma unroll
        for (int m = 0; m < 4; ++m) {
            const int ra = (wm * 64 + m * 16 + lr) * 128;
            const int rb = (wn * 64 + m * 16 + lr) * 128;
            af0[m] = *reinterpret_cast<const bf16x8*>((const char*)As + ra + slotA0);
            af1[m] = *reinterpret_cast<const bf16x8*>((const char*)As + ra + slotA1);
            bf0[m] = *reinterpret_cast<const bf16x8*>((const char*)Bs + rb + slotA0);
            bf1[m] = *reinterpret_cast<const bf16x8*>((const char*)Bs + rb + slotA1);
        }
#pragma unroll
        for (int m = 0; m < 4; ++m)
#pragma unroll
            for (int n = 0; n < 4; ++n)
                acc[m][n] = __builtin_amdgcn_mfma_f32_16x16x32_bf16(af0[m], bf0[n], acc[m][n], 0, 0, 0);
#pragma unroll
        for (int m = 0; m < 4; ++m)
#pragma unroll
            for (int n = 0; n < 4; ++n)
                acc[m][n] = __builtin_amdgcn_mfma_f32_16x16x32_bf16(af1[m], bf1[n], acc[m][n], 0, 0, 0);
        __syncthreads();   // all reads done before next-iter staging overwrites
    }

    if (MODE == 0) {
#pragma unroll
        for (int m = 0; m < 4; ++m)
#pragma unroll
            for (int n = 0; n < 4; ++n) {
                const int rbase = m0 + wm * 64 + m * 16 + lk * 4;
                const int cbase = n0 + wn * 64 + n * 16 + lr;
                const int seg = cbase >> 10, e = cbase & 1023;
                if (seg < 2) {
                    unsigned short* C = (unsigned short*)(seg == 0 ? o0 : o1);
#pragma unroll
                    for (int j = 0; j < 4; ++j)
                        C[(size_t)(rbase + j) * D_ + e] = f2bf(acc[m][n][j]);
                } else {
                    unsigned short* Vt = (unsigned short*)o2;
                    const int b = rbase >> 11, nq = rbase & 2047;
                    ushort4 pk;
                    pk.x = f2bf(acc[m][n][0]); pk.y = f2bf(acc[m][n][1]);
                    pk.z = f2bf(acc[m][n][2]); pk.w = f2bf(acc[m][n][3]);
                    *reinterpret_cast<ushort4*>(&Vt[(((size_t)b << 10) + e) * NSEQ + nq]) = pk;
                }
            }
    } else if (MODE == 2) {
        // scale + mask into acc, store S bf16
        unsigned short* S = (unsigned short*)o0 + (size_t)bz * NSEQ * NSEQ;
#pragma unroll
        for (int m = 0; m < 4; ++m)
#pragma unroll
            for (int n = 0; n < 4; ++n) {
                const int rbase = m0 + wm * 64 + m * 16 + lk * 4;
                const int cbase = n0 + wn * 64 + n * 16 + lr;
#pragma unroll
                for (int j = 0; j < 4; ++j) {
                    float s = acc[m][n][j] * 0.03125f;    // 1/sqrt(1024)
                    if (cbase > rbase + j) s = -1e30f;
                    acc[m][n][j] = s;
                    S[(size_t)(rbase + j) * NSEQ + cbase] = f2bf(s);
                }
            }
        // per-(row, 64-col slice) partial softmax stats; slice index = by*2 + wn
        float* Pm = (float*)o1;
        float* Pl = (float*)o2;
        const int pcol = by * 2 + wn;
#pragma unroll
        for (int m = 0; m < 4; ++m)
#pragma unroll
            for (int j = 0; j < 4; ++j) {
                float mx = fmaxf(fmaxf(acc[m][0][j], acc[m][1][j]),
                                 fmaxf(acc[m][2][j], acc[m][3][j]));
#pragma unroll
                for (int w = 1; w < 16; w <<= 1) mx = fmaxf(mx, __shfl_xor(mx, w, 64));
                float sm = __expf(acc[m][0][j] - mx) + __expf(acc[m][1][j] - mx) +
                           __expf(acc[m][2][j] - mx) + __expf(acc[m][3][j] - mx);
#pragma unroll
                for (int w = 1; w < 16; w <<= 1) sm += __shfl_xor(sm, w, 64);
                if (lr == 0) {
                    const int row = bz * NSEQ + m0 + wm * 64 + m * 16 + lk * 4 + j;
                    Pm[row * 32 + pcol] = mx;
                    Pl[row * 32 + pcol] = sm;
                }
            }
    } else {
        float* O = (float*)o0 + (size_t)bz * NSEQ * D_;
#pragma unroll
        for (int m = 0; m < 4; ++m)
#pragma unroll
            for (int n = 0; n < 4; ++n) {
                const int rbase = m0 + wm * 64 + m * 16 + lk * 4;
                const int cbase = n0 + wn * 64 + n * 16 + lr;
#pragma unroll
                for (int j = 0; j < 4; ++j)
                    O[(size_t)(rbase + j) * D_ + cbase] =
                        acc[m][n][j] * rl[bz * NSEQ + rbase + j].y;
            }
    }
}

// ---------------- merge partial stats + one-pass exp: P bf16 = exp(S - m), in place (S bf16) ----------------
__global__ __launch_bounds__(256) void softmax_finish(unsigned short* __restrict__ S,
                                                      const float* __restrict__ Pm,
                                                      const float* __restrict__ Pl,
                                                      float2* __restrict__ rl) {
    const int lane = threadIdx.x & 63;
    const int row = blockIdx.x * 4 + (threadIdx.x >> 6);   // 0..8191
    const int q = row & 2047;
    const int nb = (q >> 7) + 1;      // causal extent in 128-blocks
    const int nc = nb * 2;            // 64-col slices, <= 32

    // merge partials across the wave (lane = slice index)
    float mb = (lane < nc) ? Pm[row * 32 + lane] : -3e38f;
    float m = mb;
#pragma unroll
    for (int off = 32; off > 0; off >>= 1) m = fmaxf(m, __shfl_xor(m, off, 64));
    float lb = (lane < nc) ? Pl[row * 32 + lane] * __expf(mb - m) : 0.f;
#pragma unroll
    for (int off = 32; off > 0; off >>= 1) lb += __shfl_xor(lb, off, 64);
    if (lane == 0) rl[row] = make_float2(m, 1.0f / lb);

    // one-pass exp transform in place: 16B reads, 16B writes (single wave owns the row)
    unsigned short* srow = S + (size_t)row * NSEQ;
    const int L = nb << 7;
    for (int k = lane * 8; k < L; k += 512) {
        ushort4 a = *reinterpret_cast<const ushort4*>(srow + k);
        ushort4 b = *reinterpret_cast<const ushort4*>(srow + k + 4);
        ushort4 pa, pb;
        pa.x = f2bf(__expf(bf2f(a.x) - m)); pa.y = f2bf(__expf(bf2f(a.y) - m));
        pa.z = f2bf(__expf(bf2f(a.z) - m)); pa.w = f2bf(__expf(bf2f(a.w) - m));
        pb.x = f2bf(__expf(bf2f(b.x) - m)); pb.y = f2bf(__expf(bf2f(b.y) - m));
        pb.z = f2bf(__expf(bf2f(b.z) - m)); pb.w = f2bf(__expf(bf2f(b.w) - m));
        *reinterpret_cast<ushort4*>(srow + k)     = pa;
        *reinterpret_cast<ushort4*>(srow + k + 4) = pb;
    }
}

extern "C" void kernel_launch(void* const* d_in, const int* in_sizes, int n_in,
                              void* d_out, int out_size, void* d_ws, size_t ws_size,
                              hipStream_t stream) {
    const float* x  = (const float*)d_in[0];
    const float* Wq = (const float*)d_in[1];
    const float* Wk = (const float*)d_in[2];
    const float* Wv = (const float*)d_in[3];

    char* ws = (char*)d_ws;
    unsigned short* S    = (unsigned short*)(ws);               // 32 MiB (bf16)
    __hip_bfloat16* Xb   = (__hip_bfloat16*)(ws + 67108864);    // 16 MiB (dead after QKV)
    __hip_bfloat16* Q    = (__hip_bfloat16*)(ws + 83886080);    // 16 MiB
    __hip_bfloat16* K    = (__hip_bfloat16*)(ws + 100663296);   // 16 MiB
    __hip_bfloat16* Vt   = (__hip_bfloat16*)(ws + 117440512);   // 16 MiB
    __hip_bfloat16* Wt   = (__hip_bfloat16*)(ws + 134217728);   // 6 MiB
    // partial-stat buffers overlay the Xb region (only needed after QKV consumed Xb)
    float*  Pm = (float*)(ws + 67108864);                       // 1 MiB
    float*  Pl = (float*)(ws + 68157440);                       // 1 MiB
    float2* rl = (float2*)(ws + 69206016);                      // 64 KiB

    cvt_x<<<8192, 256, 0, stream>>>(x, Xb);
    wt_kernel<<<dim3(32, 32, 3), 256, 0, stream>>>(Wq, Wk, Wv, Wt);

    // fused QKV: [8192,1024] x [3072,1024]^T
    gemm128<0><<<dim3(64, 24, 1), 256, 0, stream>>>(Xb, 1024, Wt, 1024, Q, K, Vt, nullptr);

    // scores + partial softmax stats (flat lower-triangle enumeration: 136 tiles x 4 batches)
    gemm128<2><<<dim3(544), 256, 0, stream>>>(Q, 1024, K, 1024, S, Pm, Pl, nullptr);
    // merge stats + exp transform (S bf16 -> P bf16 in place)
    softmax_finish<<<2048, 256, 0, stream>>>(S, Pm, Pl, rl);
    // PV (flat grid, anti-correlated Kdim pairing); A = P bf16 (lda 2048)
    gemm128<3><<<dim3(512), 256, 0, stream>>>((const __hip_bfloat16*)S, 2048, Vt, 2048,
                                              d_out, nullptr, nullptr, rl);
}